// Round 3
// baseline (188.043 us; speedup 1.0000x reference)
//
#include <hip/hip_runtime.h>

// ---------------------------------------------------------------------------
// SpatialWiseSelfAttention on MI355X (gfx950), bf16 MFMA pipeline.
//   x[16,512,32,32] -> xf[8192,1024]
//   Q/K/V = xf @ W*.T + b*      (NT GEMM, bf16 inputs, fp32 accum)
//   per (b,h): S = Q K^T / 8 ; P = softmax(S) ; O = P V
//   out = O @ Wo.T + bo  (fp32 out)
// GEMMs: 128x256 tile, BK=64, 8 waves (2Mx4N), 32x32x16 MFMA, 3-buffer LDS
// rotation, ONE s_barrier per K-tile, counted vmcnt(6) (never 0 mid-loop).
// ---------------------------------------------------------------------------

typedef unsigned short u16;
typedef __attribute__((ext_vector_type(8))) short short8;   // 8 bf16 = 4 VGPR
typedef __attribute__((ext_vector_type(4))) float f32x4;
typedef __attribute__((ext_vector_type(16))) float f32x16;
typedef __attribute__((ext_vector_type(4))) unsigned short u16x4;

#define MFMA16(a, b, c) __builtin_amdgcn_mfma_f32_16x16x32_bf16(a, b, c, 0, 0, 0)
#define MFMA32(a, b, c) __builtin_amdgcn_mfma_f32_32x32x16_bf16(a, b, c, 0, 0, 0)

__device__ __forceinline__ u16 f2bf(float x) {            // RNE f32->bf16
  unsigned u = __float_as_uint(x);
  u += 0x7FFFu + ((u >> 16) & 1u);
  return (u16)(u >> 16);
}

__device__ __forceinline__ void async16(const void* g, void* l) {
  // 16B global->LDS direct; LDS dest = wave-uniform base + lane*16.
  __builtin_amdgcn_global_load_lds(
      (__attribute__((address_space(1))) unsigned int*)(g),
      (__attribute__((address_space(3))) unsigned int*)(l), 16, 0, 0);
}

// ---------------------------------------------------------------------------
// Fused fp32 -> bf16 conversion of x + Wq + Wk + Wv + Wo.
// Destinations are contiguous in workspace: xb | wqb | wkb | wvb | wob.
// One group = 4 floats. x: 2097152 groups, each W: 262144 groups.
// ---------------------------------------------------------------------------
__global__ __launch_bounds__(256) void cvt_all(
    const float* __restrict__ x, const float* __restrict__ wq,
    const float* __restrict__ wk, const float* __restrict__ wv,
    const float* __restrict__ wo, u16* __restrict__ dst) {
  int g = blockIdx.x * 256 + threadIdx.x;   // global group id (12288*256 total)
  const float* s;
  int off;
  if (g < 2097152) {
    s = x; off = g;
  } else {
    int r = g - 2097152;
    int w = r >> 18;            // 262144 groups per weight
    off = r & 262143;
    s = (w == 0) ? wq : (w == 1) ? wk : (w == 2) ? wv : wo;
  }
  f32x4 v = ((const f32x4*)s)[off];
  u16x4 o;
#pragma unroll
  for (int j = 0; j < 4; ++j) o[j] = f2bf(v[j]);
  ((u16x4*)dst)[g] = o;
}

// ---------------------------------------------------------------------------
// Pipelined NT GEMM core. C-tile 128(M)x256(N), BK=64, K=1024 (16 K-tiles).
// 512 thr / 8 waves as 2(M)x4(N); per-wave 64x64 = 2x2 frags of 32x32x16.
// LDS: 3 buffers x { A[128][64] + B[256][64] } bf16, XOR-swizzled
//   (16B slot ^= row&7), staged linearly by global_load_lds from the
//   pre-swizzled global source. 144 KiB total.
// Per K-tile: { 16x ds_read_b128 | stage 6 loads (tile t+2) | setprio(1)
//   16x MFMA32 setprio(0) | vmcnt(6) | s_barrier }.  One barrier per tile.
// ---------------------------------------------------------------------------
__device__ __forceinline__ void gemm32(const u16* __restrict__ A,
                                       const u16* __restrict__ W,
                                       int m0, int n0, u16* lds,
                                       f32x16 acc[2][2]) {
  const int t = threadIdx.x;
  const int wave = t >> 6, lane = t & 63, r31 = lane & 31, l5 = lane >> 5;
  const int wr = wave >> 2, wn = wave & 3;
  // staging: thread t covers LDS row srow = t>>3, 16B slot t&7 of each 64-row
  // panel; pre-swizzled source col-chunk = (t&7) ^ (srow&7).
  const int srow = t >> 3;
  const int scol = ((t & 7) ^ ((t >> 3) & 7)) << 3;
  const u16* gA = A + (size_t)(m0 + srow) * 1024 + scol;
  const u16* gB = W + (size_t)(n0 + srow) * 1024 + scol;
  u16* stA = lds + wave * 512;          // + buf*24576 (+4096 for rows 64..127)
  u16* stB = lds + 8192 + wave * 512;   // + buf*24576 + j*4096
  // A-frag (mf, ks): elem (wr*64+mf*32+r31)*64 + ((ks*2+l5)^(r31&7))*8
  const int xk = r31 & 7;
  const int arow = (wr * 64 + r31) * 64;
  const int brow = 8192 + (wn * 64 + r31) * 64;
  int soff[4];
#pragma unroll
  for (int ks = 0; ks < 4; ++ks) soff[ks] = ((ks * 2 + l5) ^ xk) << 3;

#define STAGEA(buf, k0)                                     \
  {                                                         \
    async16(gA + (k0), stA + (buf) * 24576);                \
    async16(gA + 65536 + (k0), stA + (buf) * 24576 + 4096); \
  }
#define STAGEB(buf, k0)                                                   \
  {                                                                       \
    async16(gB + (k0), stB + (buf) * 24576);                              \
    async16(gB + 65536 + (k0), stB + (buf) * 24576 + 4096);               \
    async16(gB + 131072 + (k0), stB + (buf) * 24576 + 8192);              \
    async16(gB + 196608 + (k0), stB + (buf) * 24576 + 12288);             \
  }

  // Prologue: stage K-tiles 0 and 1 (6 loads each).
  STAGEA(0, 0); STAGEB(0, 0);
  STAGEA(1, 64); STAGEB(1, 64);
  asm volatile("s_waitcnt vmcnt(6)" ::: "memory");  // tile 0 complete
  __builtin_amdgcn_s_barrier();

#pragma unroll
  for (int tt = 0; tt < 16; ++tt) {
    const u16* bufp = lds + (tt % 3) * 24576;
    short8 av[2][4], bv[2][4];
#pragma unroll
    for (int ks = 0; ks < 4; ++ks) {
      av[0][ks] = *(const short8*)(bufp + arow + soff[ks]);
      av[1][ks] = *(const short8*)(bufp + arow + 2048 + soff[ks]);
      bv[0][ks] = *(const short8*)(bufp + brow + soff[ks]);
      bv[1][ks] = *(const short8*)(bufp + brow + 2048 + soff[ks]);
    }
    if (tt < 14) {                      // stage tile tt+2 into buf (tt+2)%3
      const int nb = (tt + 2) % 3, kn = (tt + 2) * 64;
      STAGEA(nb, kn); STAGEB(nb, kn);
    }
    __builtin_amdgcn_s_setprio(1);
#pragma unroll
    for (int ks = 0; ks < 4; ++ks)
#pragma unroll
      for (int mf = 0; mf < 2; ++mf)
#pragma unroll
        for (int nf = 0; nf < 2; ++nf)
          acc[mf][nf] = MFMA32(av[mf][ks], bv[nf][ks], acc[mf][nf]);
    __builtin_amdgcn_s_setprio(0);
    // boundary: tile tt+1's 6 loads must be done; keep tile tt+2's in flight.
    if (tt < 14) {
      asm volatile("s_waitcnt vmcnt(6)" ::: "memory");
    } else {
      asm volatile("s_waitcnt vmcnt(0)" ::: "memory");
    }
    __builtin_amdgcn_s_barrier();
  }
#undef STAGEA
#undef STAGEB
}

// QKV fused: linear grid 768 = 64 m-tiles x 4 n-tiles x 3 z, XCD-swizzled.
// Q,K out layout [b,h,c,d]; V out [b,h,d,c] (transposed for attention PV).
__global__ __launch_bounds__(512, 2) void gemm_qkv(
    const u16* __restrict__ xb, const u16* __restrict__ wq,
    const u16* __restrict__ wk, const u16* __restrict__ wv,
    const float* __restrict__ bq, const float* __restrict__ bk,
    const float* __restrict__ bv, u16* __restrict__ qo, u16* __restrict__ ko,
    u16* __restrict__ vo) {
  __shared__ u16 lds[73728];  // 144 KiB
  const int id = blockIdx.x;
  const int lid = (id & 7) * 96 + (id >> 3);  // bijective XCD swizzle (768%8==0)
  const int z = lid >> 8;
  const int rem = lid & 255;
  const int m0 = (rem >> 2) * 128, n0 = (rem & 3) * 256;
  const u16* W = (z == 0) ? wq : (z == 1) ? wk : wv;
  const float* bias = (z == 0) ? bq : (z == 1) ? bk : bv;
  u16* outp = (z == 0) ? qo : (z == 1) ? ko : vo;
  f32x16 acc[2][2];
#pragma unroll
  for (int i = 0; i < 2; ++i)
#pragma unroll
    for (int j = 0; j < 2; ++j)
#pragma unroll
      for (int r = 0; r < 16; ++r) acc[i][j][r] = 0.f;
  gemm32(xb, W, m0, n0, lds, acc);

  const int t = threadIdx.x;
  const int wave = t >> 6, lane = t & 63, r31 = lane & 31, l5 = lane >> 5;
  const int wr = wave >> 2, wn = wave & 3;
  float bb[2];
#pragma unroll
  for (int nf = 0; nf < 2; ++nf) bb[nf] = bias[n0 + wn * 64 + nf * 32 + r31];
#pragma unroll
  for (int mf = 0; mf < 2; ++mf)
#pragma unroll
    for (int nf = 0; nf < 2; ++nf)
#pragma unroll
      for (int r = 0; r < 16; ++r) {
        // C/D 32x32: col = lane&31, row = (r&3) + 8*(r>>2) + 4*(lane>>5)
        int m = m0 + wr * 64 + mf * 32 + (r & 3) + ((r >> 2) << 3) + (l5 << 2);
        int n = n0 + wn * 64 + nf * 32 + r31;
        float val = acc[mf][nf][r] + bb[nf];
        int b_ = m >> 9, c = m & 511, h = n >> 6, dd = n & 63;
        int idx = (z == 2) ? ((((b_ << 4) + h) << 15) + (dd << 9) + c)
                           : ((((b_ << 4) + h) << 15) + (c << 6) + dd);
        outp[idx] = f2bf(val);
      }
}

// Output projection: fp32 out + bias, linear [8192][1024]. Grid 256.
__global__ __launch_bounds__(512, 2) void gemm_oproj(const u16* __restrict__ ab,
                                                     const u16* __restrict__ wo,
                                                     const float* __restrict__ bo,
                                                     float* __restrict__ out) {
  __shared__ u16 lds[73728];
  const int id = blockIdx.x;
  const int lid = (id & 7) * 32 + (id >> 3);  // 256%8==0
  const int m0 = (lid >> 2) * 128, n0 = (lid & 3) * 256;
  f32x16 acc[2][2];
#pragma unroll
  for (int i = 0; i < 2; ++i)
#pragma unroll
    for (int j = 0; j < 2; ++j)
#pragma unroll
      for (int r = 0; r < 16; ++r) acc[i][j][r] = 0.f;
  gemm32(ab, wo, m0, n0, lds, acc);

  const int t = threadIdx.x;
  const int wave = t >> 6, lane = t & 63, r31 = lane & 31, l5 = lane >> 5;
  const int wr = wave >> 2, wn = wave & 3;
  float bb[2];
#pragma unroll
  for (int nf = 0; nf < 2; ++nf) bb[nf] = bo[n0 + wn * 64 + nf * 32 + r31];
#pragma unroll
  for (int mf = 0; mf < 2; ++mf)
#pragma unroll
    for (int nf = 0; nf < 2; ++nf)
#pragma unroll
      for (int r = 0; r < 16; ++r) {
        int m = m0 + wr * 64 + mf * 32 + (r & 3) + ((r >> 2) << 3) + (l5 << 2);
        int n = n0 + wn * 64 + nf * 32 + r31;
        out[m * 1024 + n] = acc[mf][nf][r] + bb[nf];
      }
}

// ---------------------------------------------------------------------------
// Attention: one block per (b,h). 512 thr / 8 waves. K[512][64] and
// V^T[64][512] resident in LDS (XOR slot-swizzle: elem = row*RS + (slot^(row&7))*8).
// Each wave: 4 q-tiles of 16 rows; S (16x512) in regs; softmax in-register;
// P re-fragmented via 2KB/wave LDS buffer for PV MFMA. O = P V / rowsum.
// ---------------------------------------------------------------------------
__global__ __launch_bounds__(512, 2) void attn_kernel(
    const u16* __restrict__ qb, const u16* __restrict__ kb,
    const u16* __restrict__ vb, u16* __restrict__ ab) {
  __shared__ u16 lK[32768];   // [512 rows][64] swizzled (64 KB)
  __shared__ u16 lV[32768];   // [64 rows][512] swizzled (64 KB)
  __shared__ u16 lP[8192];    // 8 waves x [16][64] swizzled (16 KB)
  const int t = threadIdx.x;
  const int bh = blockIdx.x;
  const int b_ = bh >> 4, h_ = bh & 15;
  const u16* kg = kb + bh * 32768;
  const u16* vg = vb + bh * 32768;
#pragma unroll
  for (int i = 0; i < 8; ++i) {
    int row = i * 64 + (t >> 3), slot = t & 7;            // K: 64 rows/iter
    short8 kv = *(const short8*)(kg + row * 64 + slot * 8);
    *(short8*)(lK + row * 64 + ((slot ^ (row & 7)) << 3)) = kv;
    int vrow = i * 8 + (t >> 6), vslot = t & 63;          // V^T: 8 rows/iter
    short8 vv = *(const short8*)(vg + vrow * 512 + vslot * 8);
    *(short8*)(lV + vrow * 512 + ((vslot ^ (vrow & 7)) << 3)) = vv;
  }
  __syncthreads();

  const int wv_ = t >> 6, lane = t & 63, lr = lane & 15, lg = lane >> 4;
  u16* lPw = lP + wv_ * 1024;
  const u16* qg = qb + bh * 32768;
  const float sc = 0.125f * 1.44269504088896f;  // (1/sqrt(64)) * log2(e)

#pragma unroll 1
  for (int qi = 0; qi < 4; ++qi) {
    const int qrow = (wv_ * 4 + qi) * 16;
    // Q A-frags straight from global: row=lr, k=lg*8..
    short8 a0 = *(const short8*)(qg + (qrow + lr) * 64 + lg * 8);
    short8 a1 = *(const short8*)(qg + (qrow + lr) * 64 + 32 + lg * 8);
    f32x4 s[32];
#pragma unroll
    for (int f = 0; f < 32; ++f) {
      const u16* kr = lK + (f * 16 + lr) * 64;
      short8 k0 = *(const short8*)(kr + ((lg ^ (lr & 7)) << 3));
      short8 k1 = *(const short8*)(kr + (((4 + lg) ^ (lr & 7)) << 3));
      f32x4 z4 = (f32x4){0.f, 0.f, 0.f, 0.f};
      z4 = MFMA16(a0, k0, z4);
      z4 = MFMA16(a1, k1, z4);
      s[f] = z4;                      // D: row q = lg*4+reg, col k = f*16+lr
    }
    // softmax over 512 cols; rows are (lane-local reg r) x (16-lane groups)
    float inv[4];
#pragma unroll
    for (int r = 0; r < 4; ++r) {
      float m_ = s[0][r];
#pragma unroll
      for (int f = 1; f < 32; ++f) m_ = fmaxf(m_, s[f][r]);
      m_ = fmaxf(m_, __shfl_xor(m_, 1));
      m_ = fmaxf(m_, __shfl_xor(m_, 2));
      m_ = fmaxf(m_, __shfl_xor(m_, 4));
      m_ = fmaxf(m_, __shfl_xor(m_, 8));
      float sm = 0.f;
#pragma unroll
      for (int f = 0; f < 32; ++f) {
        float e = exp2f((s[f][r] - m_) * sc);
        s[f][r] = e;
        sm += e;
      }
      sm += __shfl_xor(sm, 1);
      sm += __shfl_xor(sm, 2);
      sm += __shfl_xor(sm, 4);
      sm += __shfl_xor(sm, 8);
      inv[r] = 1.f / sm;
    }
    // PV: 8 chunks of 64 k-cols; P chunk -> LDS -> A-frags; V^T rows as B-frags
    f32x4 o[4];
#pragma unroll
    for (int i = 0; i < 4; ++i) o[i] = (f32x4){0.f, 0.f, 0.f, 0.f};
#pragma unroll
    for (int ch = 0; ch < 8; ++ch) {
#pragma unroll
      for (int cf = 0; cf < 4; ++cf)
#pragma unroll
        for (int r = 0; r < 4; ++r) {
          int q = lg * 4 + r, kc = cf * 16 + lr;
          lPw[q * 64 + (((kc >> 3) ^ (q & 7)) << 3) + (kc & 7)] =
              f2bf(s[ch * 4 + cf][r]);
        }
      asm volatile("s_waitcnt lgkmcnt(0)" ::: "memory");
      const u16* pr = lPw + lr * 64;
      short8 pa0 = *(const short8*)(pr + ((lg ^ (lr & 7)) << 3));
      short8 pa1 = *(const short8*)(pr + (((4 + lg) ^ (lr & 7)) << 3));
#pragma unroll
      for (int df = 0; df < 4; ++df) {
        const u16* vr = lV + (df * 16 + lr) * 512;
        short8 v0 = *(const short8*)(vr + (((ch * 8 + lg) ^ (lr & 7)) << 3));
        short8 v1 =
            *(const short8*)(vr + (((ch * 8 + 4 + lg) ^ (lr & 7)) << 3));
        o[df] = MFMA16(pa0, v0, o[df]);
        o[df] = MFMA16(pa1, v1, o[df]);
      }
    }
    // store O/rowsum to attn-out [b, c, h*64+d] bf16
#pragma unroll
    for (int df = 0; df < 4; ++df)
#pragma unroll
      for (int r = 0; r < 4; ++r) {
        int q = qrow + lg * 4 + r, dd = df * 16 + lr;
        ab[(b_ * 512 + q) * 1024 + h_ * 64 + dd] = f2bf(o[df][r] * inv[r]);
      }
  }
}

// ---------------------------------------------------------------------------
extern "C" void kernel_launch(void* const* d_in, const int* in_sizes, int n_in,
                              void* d_out, int out_size, void* d_ws,
                              size_t ws_size, hipStream_t stream) {
  (void)in_sizes; (void)n_in; (void)out_size;
  const float* x  = (const float*)d_in[0];
  const float* Wq = (const float*)d_in[1];
  const float* bq = (const float*)d_in[2];
  const float* Wk = (const float*)d_in[3];
  const float* bk = (const float*)d_in[4];
  const float* Wv = (const float*)d_in[5];
  const float* bv = (const float*)d_in[6];
  const float* Wo = (const float*)d_in[7];
  const float* bo = (const float*)d_in[8];
  float* out = (float*)d_out;

  // Workspace (bf16 elems): xb (reused as attn-out) | Wq,Wk,Wv,Wo | Q | K | V^T
  if (ws_size < 75497472u) return;  // 72 MB needed
  u16* xb  = (u16*)d_ws;            // 8388608 elems, dead after QKV GEMM
  u16* wqb = xb + 8388608;
  u16* wkb = wqb + 1048576;
  u16* wvb = wkb + 1048576;
  u16* wob = wvb + 1048576;
  u16* qbuf = wob + 1048576;        // [b,h,c,d]
  u16* kbuf = qbuf + 8388608;       // [b,h,c,d]
  u16* vbuf = kbuf + 8388608;       // [b,h,d,c]
  u16* abuf = xb;                   // attn-out [b,c,e], aliases dead xb

  cvt_all<<<12288, 256, 0, stream>>>(x, Wq, Wk, Wv, Wo, xb);
  gemm_qkv<<<768, 512, 0, stream>>>(xb, wqb, wkb, wvb, bq, bk, bv,
                                    qbuf, kbuf, vbuf);
  attn_kernel<<<256, 512, 0, stream>>>(qbuf, kbuf, vbuf, abuf);
  gemm_oproj<<<256, 512, 0, stream>>>(abuf, wob, bo, out);
}

// Round 4
// 167.607 us; speedup vs baseline: 1.1219x; 1.1219x over previous
//
#include <hip/hip_runtime.h>

// ---------------------------------------------------------------------------
// SpatialWiseSelfAttention on MI355X (gfx950), bf16 MFMA pipeline.
//   x[16,512,32,32] -> xf[8192,1024]
//   Q/K/V = xf @ W*.T + b*      (NT GEMM, bf16 inputs, fp32 accum)
//   per (b,h): S = Q K^T / 8 ; P = softmax(S) ; O = P V
//   out = O @ Wo.T + bo  (fp32 out)
// GEMMs: 128x256 tile, BK=64, 8 waves (2Mx4N), 16x16x32 MFMA, m201-style
// 2-phase/K-tile schedule: {8 ds_read | 3 DMA | barrier | lgkm0 | 16 MFMA |
// barrier} x2, counted vmcnt(6) once per tile, 3-buffer LDS rotation.
// ---------------------------------------------------------------------------

typedef unsigned short u16;
typedef __attribute__((ext_vector_type(8))) short short8;   // 8 bf16 = 4 VGPR
typedef __attribute__((ext_vector_type(4))) float f32x4;
typedef __attribute__((ext_vector_type(4))) unsigned short u16x4;

#define MFMA16(a, b, c) __builtin_amdgcn_mfma_f32_16x16x32_bf16(a, b, c, 0, 0, 0)

__device__ __forceinline__ u16 f2bf(float x) {            // RNE f32->bf16
  unsigned u = __float_as_uint(x);
  u += 0x7FFFu + ((u >> 16) & 1u);
  return (u16)(u >> 16);
}

__device__ __forceinline__ void async16(const void* g, void* l) {
  // 16B global->LDS direct; LDS dest = wave-uniform base + lane*16.
  __builtin_amdgcn_global_load_lds(
      (__attribute__((address_space(1))) unsigned int*)(g),
      (__attribute__((address_space(3))) unsigned int*)(l), 16, 0, 0);
}

// ---------------------------------------------------------------------------
// Fused fp32 -> bf16 conversion of x + Wq + Wk + Wv + Wo.
// Destinations are contiguous in workspace: xb | wqb | wkb | wvb | wob.
// One group = 4 floats. x: 2097152 groups, each W: 262144 groups.
// ---------------------------------------------------------------------------
__global__ __launch_bounds__(256) void cvt_all(
    const float* __restrict__ x, const float* __restrict__ wq,
    const float* __restrict__ wk, const float* __restrict__ wv,
    const float* __restrict__ wo, u16* __restrict__ dst) {
  int g = blockIdx.x * 256 + threadIdx.x;   // global group id (12288*256 total)
  const float* s;
  int off;
  if (g < 2097152) {
    s = x; off = g;
  } else {
    int r = g - 2097152;
    int w = r >> 18;            // 262144 groups per weight
    off = r & 262143;
    s = (w == 0) ? wq : (w == 1) ? wk : (w == 2) ? wv : wo;
  }
  f32x4 v = ((const f32x4*)s)[off];
  u16x4 o;
#pragma unroll
  for (int j = 0; j < 4; ++j) o[j] = f2bf(v[j]);
  ((u16x4*)dst)[g] = o;
}

// ---------------------------------------------------------------------------
// Pipelined NT GEMM core. C-tile 128(M)x256(N), BK=64, K=1024 (16 K-tiles).
// 512 thr / 8 waves as 2(M)x4(N); per-wave 64x64 = 4x4 frags of 16x16x32.
// LDS: 3 buffers x { A[128][64] + B[256][64] } bf16, XOR-swizzled
//   (16B slot ^= row&7), staged linearly by global_load_lds from the
//   pre-swizzled global source. 144 KiB total.
// Per K-tile, 2 phases (k-halves); per phase: 8x ds_read_b128 + 3 DMA issues
//   -> s_barrier -> lgkmcnt(0)+sched_barrier -> setprio(1) 16x MFMA
//   setprio(0) -> s_barrier.  vmcnt(6) once per tile (never 0 mid-loop).
// ---------------------------------------------------------------------------
__device__ __forceinline__ void gemm16(const u16* __restrict__ A,
                                       const u16* __restrict__ W,
                                       int m0, int n0, u16* lds,
                                       f32x4 acc[4][4]) {
  const int t = threadIdx.x;
  const int wave = t >> 6, lane = t & 63, lr = lane & 15, lg = lane >> 4;
  const int wr = wave >> 2, wn = wave & 3;
  // staging: thread t covers LDS row srow = t>>3, 16B slot t&7 of each 64-row
  // panel; pre-swizzled source col-chunk = (t&7) ^ (srow&7).
  const int srow = t >> 3;
  const int scol = ((t & 7) ^ ((t >> 3) & 7)) << 3;
  const u16* gA = A + (size_t)(m0 + srow) * 1024 + scol;
  const u16* gB = W + (size_t)(n0 + srow) * 1024 + scol;
  u16* stA = lds + wave * 512;          // + buf*24576 (+4096 for rows 64..127)
  u16* stB = lds + 8192 + wave * 512;   // + buf*24576 + j*4096
  // frag read bases (elem offsets in buffer); row&7 == lr&7 for all frags.
  const int aoff = (wr * 64 + lr) * 64;          // + mf*1024
  const int boff = 8192 + (wn * 64 + lr) * 64;   // + nf*1024
  const int sw0 = (lg ^ (lr & 7)) << 3;          // k-half 0 slot
  const int sw1 = ((4 ^ lg) ^ (lr & 7)) << 3;    // k-half 1 slot

#define STAGEA(buf, k0)                                     \
  {                                                         \
    async16(gA + (k0), stA + (buf) * 24576);                \
    async16(gA + 65536 + (k0), stA + (buf) * 24576 + 4096); \
  }
#define STAGEB1(buf, k0) async16(gB + (k0), stB + (buf) * 24576);
#define STAGEB3(buf, k0)                                       \
  {                                                            \
    async16(gB + 65536 + (k0), stB + (buf) * 24576 + 4096);    \
    async16(gB + 131072 + (k0), stB + (buf) * 24576 + 8192);   \
    async16(gB + 196608 + (k0), stB + (buf) * 24576 + 12288);  \
  }

  // Prologue: stage K-tiles 0 and 1 (6 loads each).
  STAGEA(0, 0); STAGEB1(0, 0); STAGEB3(0, 0);
  STAGEA(1, 64); STAGEB1(1, 64); STAGEB3(1, 64);
  asm volatile("s_waitcnt vmcnt(6)" ::: "memory");  // tile 0 complete
  __builtin_amdgcn_s_barrier();

#pragma unroll
  for (int tt = 0; tt < 16; ++tt) {
    const u16* bufp = lds + (tt % 3) * 24576;
    const int nb = (tt + 2) % 3, kn = (tt + 2) * 64;
    short8 av[4], bv[4];
    // ---------------- phase 0: k-half 0 ----------------
#pragma unroll
    for (int m = 0; m < 4; ++m)
      av[m] = *(const short8*)(bufp + aoff + m * 1024 + sw0);
#pragma unroll
    for (int n = 0; n < 4; ++n)
      bv[n] = *(const short8*)(bufp + boff + n * 1024 + sw0);
    if (tt < 14) { STAGEA(nb, kn); STAGEB1(nb, kn); }   // 3 DMA issues
    __builtin_amdgcn_s_barrier();
    asm volatile("s_waitcnt lgkmcnt(0)" ::: "memory");
    __builtin_amdgcn_sched_barrier(0);
    __builtin_amdgcn_s_setprio(1);
#pragma unroll
    for (int m = 0; m < 4; ++m)
#pragma unroll
      for (int n = 0; n < 4; ++n)
        acc[m][n] = MFMA16(av[m], bv[n], acc[m][n]);
    __builtin_amdgcn_s_setprio(0);
    __builtin_amdgcn_s_barrier();
    // ---------------- phase 1: k-half 1 ----------------
#pragma unroll
    for (int m = 0; m < 4; ++m)
      av[m] = *(const short8*)(bufp + aoff + m * 1024 + sw1);
#pragma unroll
    for (int n = 0; n < 4; ++n)
      bv[n] = *(const short8*)(bufp + boff + n * 1024 + sw1);
    if (tt < 14) STAGEB3(nb, kn);                       // 3 DMA issues
    __builtin_amdgcn_s_barrier();
    asm volatile("s_waitcnt lgkmcnt(0)" ::: "memory");
    __builtin_amdgcn_sched_barrier(0);
    __builtin_amdgcn_s_setprio(1);
#pragma unroll
    for (int m = 0; m < 4; ++m)
#pragma unroll
      for (int n = 0; n < 4; ++n)
        acc[m][n] = MFMA16(av[m], bv[n], acc[m][n]);
    __builtin_amdgcn_s_setprio(0);
    // boundary: tile tt+1's 6 loads must be done; keep tile tt+2's in flight.
    if (tt < 14) {
      asm volatile("s_waitcnt vmcnt(6)" ::: "memory");
    } else {
      asm volatile("s_waitcnt vmcnt(0)" ::: "memory");
    }
    __builtin_amdgcn_s_barrier();
  }
#undef STAGEA
#undef STAGEB1
#undef STAGEB3
}

// QKV fused: linear grid 768 = 64 m-tiles x 4 n-tiles x 3 z, XCD-swizzled.
// Q,K out layout [b,h,c,d]; V out [b,h,d,c] (transposed for attention PV).
__global__ __launch_bounds__(512, 2) void gemm_qkv(
    const u16* __restrict__ xb, const u16* __restrict__ wq,
    const u16* __restrict__ wk, const u16* __restrict__ wv,
    const float* __restrict__ bq, const float* __restrict__ bk,
    const float* __restrict__ bv, u16* __restrict__ qo, u16* __restrict__ ko,
    u16* __restrict__ vo) {
  __shared__ u16 lds[73728];  // 144 KiB
  const int id = blockIdx.x;
  const int lid = (id & 7) * 96 + (id >> 3);  // bijective XCD swizzle (768%8==0)
  const int z = lid >> 8;
  const int rem = lid & 255;
  const int m0 = (rem >> 2) * 128, n0 = (rem & 3) * 256;
  const u16* W = (z == 0) ? wq : (z == 1) ? wk : wv;
  const float* bias = (z == 0) ? bq : (z == 1) ? bk : bv;
  u16* outp = (z == 0) ? qo : (z == 1) ? ko : vo;
  f32x4 acc[4][4];
#pragma unroll
  for (int i = 0; i < 4; ++i)
#pragma unroll
    for (int j = 0; j < 4; ++j) acc[i][j] = (f32x4){0.f, 0.f, 0.f, 0.f};
  gemm16(xb, W, m0, n0, lds, acc);

  const int t = threadIdx.x;
  const int wave = t >> 6, lane = t & 63, lr = lane & 15, lg = lane >> 4;
  const int wr = wave >> 2, wn = wave & 3;
  float bb[4];
#pragma unroll
  for (int nf = 0; nf < 4; ++nf) bb[nf] = bias[n0 + wn * 64 + nf * 16 + lr];
#pragma unroll
  for (int mf = 0; mf < 4; ++mf)
#pragma unroll
    for (int nf = 0; nf < 4; ++nf)
#pragma unroll
      for (int r = 0; r < 4; ++r) {
        int m = m0 + wr * 64 + mf * 16 + lg * 4 + r;  // D: row=(lane>>4)*4+reg
        int n = n0 + wn * 64 + nf * 16 + lr;          //    col=lane&15
        float val = acc[mf][nf][r] + bb[nf];
        int b_ = m >> 9, c = m & 511, h = n >> 6, dd = n & 63;
        int idx = (z == 2) ? ((((b_ << 4) + h) << 15) + (dd << 9) + c)
                           : ((((b_ << 4) + h) << 15) + (c << 6) + dd);
        outp[idx] = f2bf(val);
      }
}

// Output projection: fp32 out + bias, linear [8192][1024]. Grid 256.
__global__ __launch_bounds__(512, 2) void gemm_oproj(const u16* __restrict__ ab,
                                                     const u16* __restrict__ wo,
                                                     const float* __restrict__ bo,
                                                     float* __restrict__ out) {
  __shared__ u16 lds[73728];
  const int id = blockIdx.x;
  const int lid = (id & 7) * 32 + (id >> 3);  // 256%8==0
  const int m0 = (lid >> 2) * 128, n0 = (lid & 3) * 256;
  f32x4 acc[4][4];
#pragma unroll
  for (int i = 0; i < 4; ++i)
#pragma unroll
    for (int j = 0; j < 4; ++j) acc[i][j] = (f32x4){0.f, 0.f, 0.f, 0.f};
  gemm16(ab, wo, m0, n0, lds, acc);

  const int t = threadIdx.x;
  const int wave = t >> 6, lane = t & 63, lr = lane & 15, lg = lane >> 4;
  const int wr = wave >> 2, wn = wave & 3;
  float bb[4];
#pragma unroll
  for (int nf = 0; nf < 4; ++nf) bb[nf] = bo[n0 + wn * 64 + nf * 16 + lr];
#pragma unroll
  for (int mf = 0; mf < 4; ++mf)
#pragma unroll
    for (int nf = 0; nf < 4; ++nf)
#pragma unroll
      for (int r = 0; r < 4; ++r) {
        int m = m0 + wr * 64 + mf * 16 + lg * 4 + r;
        int n = n0 + wn * 64 + nf * 16 + lr;
        out[m * 1024 + n] = acc[mf][nf][r] + bb[nf];
      }
}

// ---------------------------------------------------------------------------
// Attention: one block per (b,h). 512 thr / 8 waves. K[512][64] and
// V^T[64][512] resident in LDS (XOR slot-swizzle: elem = row*RS + (slot^(row&7))*8).
// Each wave: 4 q-tiles of 16 rows; S (16x512) in regs; softmax in-register;
// P re-fragmented via 2KB/wave LDS buffer for PV MFMA. O = P V / rowsum.
// ---------------------------------------------------------------------------
__global__ __launch_bounds__(512, 2) void attn_kernel(
    const u16* __restrict__ qb, const u16* __restrict__ kb,
    const u16* __restrict__ vb, u16* __restrict__ ab) {
  __shared__ u16 lK[32768];   // [512 rows][64] swizzled (64 KB)
  __shared__ u16 lV[32768];   // [64 rows][512] swizzled (64 KB)
  __shared__ u16 lP[8192];    // 8 waves x [16][64] swizzled (16 KB)
  const int t = threadIdx.x;
  const int bh = blockIdx.x;
  const int b_ = bh >> 4, h_ = bh & 15;
  const u16* kg = kb + bh * 32768;
  const u16* vg = vb + bh * 32768;
#pragma unroll
  for (int i = 0; i < 8; ++i) {
    int row = i * 64 + (t >> 3), slot = t & 7;            // K: 64 rows/iter
    short8 kv = *(const short8*)(kg + row * 64 + slot * 8);
    *(short8*)(lK + row * 64 + ((slot ^ (row & 7)) << 3)) = kv;
    int vrow = i * 8 + (t >> 6), vslot = t & 63;          // V^T: 8 rows/iter
    short8 vv = *(const short8*)(vg + vrow * 512 + vslot * 8);
    *(short8*)(lV + vrow * 512 + ((vslot ^ (vrow & 7)) << 3)) = vv;
  }
  __syncthreads();

  const int wv_ = t >> 6, lane = t & 63, lr = lane & 15, lg = lane >> 4;
  u16* lPw = lP + wv_ * 1024;
  const u16* qg = qb + bh * 32768;
  const float sc = 0.125f * 1.44269504088896f;  // (1/sqrt(64)) * log2(e)

#pragma unroll 1
  for (int qi = 0; qi < 4; ++qi) {
    const int qrow = (wv_ * 4 + qi) * 16;
    // Q A-frags straight from global: row=lr, k=lg*8..
    short8 a0 = *(const short8*)(qg + (qrow + lr) * 64 + lg * 8);
    short8 a1 = *(const short8*)(qg + (qrow + lr) * 64 + 32 + lg * 8);
    f32x4 s[32];
#pragma unroll
    for (int f = 0; f < 32; ++f) {
      const u16* kr = lK + (f * 16 + lr) * 64;
      short8 k0 = *(const short8*)(kr + ((lg ^ (lr & 7)) << 3));
      short8 k1 = *(const short8*)(kr + (((4 + lg) ^ (lr & 7)) << 3));
      f32x4 z4 = (f32x4){0.f, 0.f, 0.f, 0.f};
      z4 = MFMA16(a0, k0, z4);
      z4 = MFMA16(a1, k1, z4);
      s[f] = z4;                      // D: row q = lg*4+reg, col k = f*16+lr
    }
    // softmax over 512 cols; rows are (lane-local reg r) x (16-lane groups)
    float inv[4];
#pragma unroll
    for (int r = 0; r < 4; ++r) {
      float m_ = s[0][r];
#pragma unroll
      for (int f = 1; f < 32; ++f) m_ = fmaxf(m_, s[f][r]);
      m_ = fmaxf(m_, __shfl_xor(m_, 1));
      m_ = fmaxf(m_, __shfl_xor(m_, 2));
      m_ = fmaxf(m_, __shfl_xor(m_, 4));
      m_ = fmaxf(m_, __shfl_xor(m_, 8));
      float sm = 0.f;
#pragma unroll
      for (int f = 0; f < 32; ++f) {
        float e = exp2f((s[f][r] - m_) * sc);
        s[f][r] = e;
        sm += e;
      }
      sm += __shfl_xor(sm, 1);
      sm += __shfl_xor(sm, 2);
      sm += __shfl_xor(sm, 4);
      sm += __shfl_xor(sm, 8);
      inv[r] = 1.f / sm;
    }
    // PV: 8 chunks of 64 k-cols; P chunk -> LDS -> A-frags; V^T rows as B-frags
    f32x4 o[4];
#pragma unroll
    for (int i = 0; i < 4; ++i) o[i] = (f32x4){0.f, 0.f, 0.f, 0.f};
#pragma unroll
    for (int ch = 0; ch < 8; ++ch) {
#pragma unroll
      for (int cf = 0; cf < 4; ++cf)
#pragma unroll
        for (int r = 0; r < 4; ++r) {
          int q = lg * 4 + r, kc = cf * 16 + lr;
          lPw[q * 64 + (((kc >> 3) ^ (q & 7)) << 3) + (kc & 7)] =
              f2bf(s[ch * 4 + cf][r]);
        }
      asm volatile("s_waitcnt lgkmcnt(0)" ::: "memory");
      const u16* pr = lPw + lr * 64;
      short8 pa0 = *(const short8*)(pr + ((lg ^ (lr & 7)) << 3));
      short8 pa1 = *(const short8*)(pr + (((4 + lg) ^ (lr & 7)) << 3));
#pragma unroll
      for (int df = 0; df < 4; ++df) {
        const u16* vr = lV + (df * 16 + lr) * 512;
        short8 v0 = *(const short8*)(vr + (((ch * 8 + lg) ^ (lr & 7)) << 3));
        short8 v1 =
            *(const short8*)(vr + (((ch * 8 + 4 + lg) ^ (lr & 7)) << 3));
        o[df] = MFMA16(pa0, v0, o[df]);
        o[df] = MFMA16(pa1, v1, o[df]);
      }
    }
    // store O/rowsum to attn-out [b, c, h*64+d] bf16
#pragma unroll
    for (int df = 0; df < 4; ++df)
#pragma unroll
      for (int r = 0; r < 4; ++r) {
        int q = qrow + lg * 4 + r, dd = df * 16 + lr;
        ab[(b_ * 512 + q) * 1024 + h_ * 64 + dd] = f2bf(o[df][r] * inv[r]);
      }
  }
}

// ---------------------------------------------------------------------------
extern "C" void kernel_launch(void* const* d_in, const int* in_sizes, int n_in,
                              void* d_out, int out_size, void* d_ws,
                              size_t ws_size, hipStream_t stream) {
  (void)in_sizes; (void)n_in; (void)out_size;
  const float* x  = (const float*)d_in[0];
  const float* Wq = (const float*)d_in[1];
  const float* bq = (const float*)d_in[2];
  const float* Wk = (const float*)d_in[3];
  const float* bk = (const float*)d_in[4];
  const float* Wv = (const float*)d_in[5];
  const float* bv = (const float*)d_in[6];
  const float* Wo = (const float*)d_in[7];
  const float* bo = (const float*)d_in[8];
  float* out = (float*)d_out;

  // Workspace (bf16 elems): xb (reused as attn-out) | Wq,Wk,Wv,Wo | Q | K | V^T
  if (ws_size < 75497472u) return;  // 72 MB needed
  u16* xb  = (u16*)d_ws;            // 8388608 elems, dead after QKV GEMM
  u16* wqb = xb + 8388608;
  u16* wkb = wqb + 1048576;
  u16* wvb = wkb + 1048576;
  u16* wob = wvb + 1048576;
  u16* qbuf = wob + 1048576;        // [b,h,c,d]
  u16* kbuf = qbuf + 8388608;       // [b,h,c,d]
  u16* vbuf = kbuf + 8388608;       // [b,h,d,c]
  u16* abuf = xb;                   // attn-out [b,c,e], aliases dead xb

  cvt_all<<<12288, 256, 0, stream>>>(x, Wq, Wk, Wv, Wo, xb);
  gemm_qkv<<<768, 512, 0, stream>>>(xb, wqb, wkb, wvb, bq, bk, bv,
                                    qbuf, kbuf, vbuf);
  attn_kernel<<<256, 512, 0, stream>>>(qbuf, kbuf, vbuf, abuf);
  gemm_oproj<<<256, 512, 0, stream>>>(abuf, wob, bo, out);
}